// Round 11
// baseline (563.897 us; speedup 1.0000x reference)
//
#include <hip/hip_runtime.h>
#include <math.h>

#define HEAD_DIM 128
#define NHEADS   32
#define SPLITS   8
#define SLEN     8192
#define CHUNK    (SLEN / SPLITS)   /* 1024 */
#define NLAYERS  32
#define PART_STRIDE (HEAD_DIM + 2) /* m, l, acc[128] */
#define KROW     (SLEN / 2)        /* K^T fp4 row bytes = 4096 */
#define VROW     (HEAD_DIM / 2)    /* V fp4 row bytes = 64 */

typedef unsigned int   uint;
typedef unsigned char  uchar;
typedef __attribute__((ext_vector_type(2))) float f2v;
typedef __attribute__((ext_vector_type(4))) float f4v;   // NT-capable float4
typedef __attribute__((ext_vector_type(2))) uint  u2v;   // NT-capable uint2

// ---- fp4 e2m1 hardware converters (gfx950), scale = 1.0 ----
__device__ __forceinline__ f2v d4_0(uint w) { return __builtin_amdgcn_cvt_scalef32_pk_f32_fp4(w, 1.0f, 0); }
__device__ __forceinline__ f2v d4_1(uint w) { return __builtin_amdgcn_cvt_scalef32_pk_f32_fp4(w, 1.0f, 1); }
__device__ __forceinline__ f2v d4_2(uint w) { return __builtin_amdgcn_cvt_scalef32_pk_f32_fp4(w, 1.0f, 2); }
__device__ __forceinline__ f2v d4_3(uint w) { return __builtin_amdgcn_cvt_scalef32_pk_f32_fp4(w, 1.0f, 3); }

__device__ __forceinline__ uint pk8_fp4(float a0, float a1, float a2, float a3,
                                        float a4, float a5, float a6, float a7) {
    uint r = 0;
    r = __builtin_amdgcn_cvt_scalef32_pk_fp4_f32(r, a0, a1, 1.0f, 0);
    r = __builtin_amdgcn_cvt_scalef32_pk_fp4_f32(r, a2, a3, 1.0f, 1);
    r = __builtin_amdgcn_cvt_scalef32_pk_fp4_f32(r, a4, a5, 1.0f, 2);
    r = __builtin_amdgcn_cvt_scalef32_pk_fp4_f32(r, a6, a7, 1.0f, 3);
    return r;
}

// ---- K: fp32 [h][s][d] -> fp4 TRANSPOSED [h][d][s] (+ optional fp32 copy-out) ----
template<bool WRITE_OUT>
__global__ __launch_bounds__(256)
void convert_kT(const float* __restrict__ k, uchar* __restrict__ kbt,
                float* __restrict__ kout)
{
    const int h   = blockIdx.x >> 7;      // 128 s-tiles of 64 per head
    const int st  = blockIdx.x & 127;
    const int tid = threadIdx.x;

    __shared__ float tile[HEAD_DIM][65];

    const int   srow0 = tid >> 5;
    const int   c4    = (tid & 31) * 4;
    const size_t kbase = ((size_t)h * SLEN + (size_t)st * 64) * HEAD_DIM;

    #pragma unroll
    for (int it = 0; it < 8; ++it) {
        const int s = srow0 + it * 8;
        const f4v v = __builtin_nontemporal_load(
            (const f4v*)(k + kbase + (size_t)s * HEAD_DIM + c4));
        if (WRITE_OUT)
            __builtin_nontemporal_store(v, (f4v*)(kout + kbase + (size_t)s * HEAD_DIM + c4));
        tile[c4 + 0][s] = v.x; tile[c4 + 1][s] = v.y;
        tile[c4 + 2][s] = v.z; tile[c4 + 3][s] = v.w;
    }
    __syncthreads();

    const int d0  = tid >> 3;
    const int sl8 = (tid & 7) * 8;
    #pragma unroll
    for (int it = 0; it < 4; ++it) {
        const int d = d0 + it * 32;
        const uint u = pk8_fp4(tile[d][sl8 + 0], tile[d][sl8 + 1],
                               tile[d][sl8 + 2], tile[d][sl8 + 3],
                               tile[d][sl8 + 4], tile[d][sl8 + 5],
                               tile[d][sl8 + 6], tile[d][sl8 + 7]);
        *(uint*)(kbt + ((size_t)h * HEAD_DIM + d) * KROW + st * 32 + (tid & 7) * 4) = u;
    }
}

// ---- V: fp32 -> fp4 row-major (+ optional fp32 copy-out) ----
template<bool WRITE_OUT>
__global__ void convert_v(const float* __restrict__ v, u2v* __restrict__ vb,
                          float* __restrict__ vout, size_t n16)
{
    size_t i = (size_t)blockIdx.x * blockDim.x + threadIdx.x;
    const size_t stride = (size_t)gridDim.x * blockDim.x;
    for (size_t j = i; j < n16; j += stride) {
        const f4v b0 = __builtin_nontemporal_load((const f4v*)(v + 16 * j));
        const f4v b1 = __builtin_nontemporal_load((const f4v*)(v + 16 * j + 4));
        const f4v b2 = __builtin_nontemporal_load((const f4v*)(v + 16 * j + 8));
        const f4v b3 = __builtin_nontemporal_load((const f4v*)(v + 16 * j + 12));
        if (WRITE_OUT) {
            __builtin_nontemporal_store(b0, (f4v*)(vout + 16 * j));
            __builtin_nontemporal_store(b1, (f4v*)(vout + 16 * j + 4));
            __builtin_nontemporal_store(b2, (f4v*)(vout + 16 * j + 8));
            __builtin_nontemporal_store(b3, (f4v*)(vout + 16 * j + 12));
        }
        u2v p;
        p.x = pk8_fp4(b0.x, b0.y, b0.z, b0.w, b1.x, b1.y, b1.z, b1.w);
        p.y = pk8_fp4(b2.x, b2.y, b2.z, b2.w, b3.x, b3.y, b3.z, b3.w);
        vb[j] = p;
    }
}

// ---- fallback copy ----
__global__ void copy_kv(const float4* __restrict__ k, const float4* __restrict__ v,
                        float4* __restrict__ out, size_t n4)
{
    size_t i = (size_t)blockIdx.x * blockDim.x + threadIdx.x;
    const size_t stride = (size_t)gridDim.x * blockDim.x;
    for (size_t j = i; j < n4; j += stride) {
        out[j]      = k[j];
        out[n4 + j] = v[j];
    }
}

__device__ __forceinline__ float combine_head(const float* __restrict__ ph, int d)
{
    float G = -3.0e38f;
    #pragma unroll
    for (int i = 0; i < SPLITS; ++i) G = fmaxf(G, ph[i * PART_STRIDE]);
    float L = 0.f, a = 0.f;
    #pragma unroll
    for (int i = 0; i < SPLITS; ++i) {
        const float wv = __expf(ph[i * PART_STRIDE] - G);
        L = fmaf(ph[i * PART_STRIDE + 1], wv, L);
        a = fmaf(ph[i * PART_STRIDE + 2 + d], wv, a);
    }
    return a / L;
}

// ---- one layer: 256 blocks (1/CU) x 512 threads; chunk = 1024 rows ----
// K d-rows 112..127 and V s-rows 896..1023 (1/8 of each) are read with
// non-temporal loads -> L2-resident set 29.3MB (3.67MB/XCD) fits stably.
__global__ __launch_bounds__(512)
void attn_layer(const float* __restrict__ x0,
                const float* __restrict__ part_in,
                const uchar* __restrict__ kbt,   // fp4 K^T [32][128][8192]
                const uchar* __restrict__ vb,    // fp4 V   [32][8192][128]
                float* __restrict__ part_out)
{
    const int h    = blockIdx.x >> 3;
    const int sp   = blockIdx.x & 7;
    const int tid  = threadIdx.x;   // 0..511
    const int lane = tid & 63;
    const int w    = tid >> 6;      // 0..7

    __shared__ float xs[HEAD_DIM];
    __shared__ float sc[CHUNK];          // scores -> probs (4 KB)
    __shared__ float scpv[8][HEAD_DIM];  // per-wave PV partials (4 KB)
    __shared__ float wred[8], lred[8];

    // ---- prologue: produce x for this head (8-split combine) ----
    if (tid < HEAD_DIM) {
        if (part_in) xs[tid] = combine_head(part_in + (size_t)h * SPLITS * PART_STRIDE, tid);
        else         xs[tid] = x0[h * HEAD_DIM + tid];
    }
    __syncthreads();

    // ---- QK: lane owns 16 consecutive s for one d per iteration ----
    const int dpar = lane >> 3;              // 0..7
    const int sg   = (w << 3) + (lane & 7);  // 0..63 (16-s group)
    const uchar* __restrict__ kh = kbt + (size_t)h * HEAD_DIM * KROW + (size_t)sp * (CHUNK / 2);
    float a16[16];
    #pragma unroll
    for (int j = 0; j < 16; ++j) a16[j] = 0.f;
    #pragma unroll
    for (int it = 0; it < 16; ++it) {
        const int d = it * 8 + dpar;
        const u2v* kp = (const u2v*)(kh + (size_t)d * KROW + sg * 8);
        const u2v kk = (it >= 14) ? __builtin_nontemporal_load(kp) : *kp;
        const float xd = xs[d];
        f2v t;
        t = d4_0(kk.x); a16[0]  = fmaf(t.x, xd, a16[0]);  a16[1]  = fmaf(t.y, xd, a16[1]);
        t = d4_1(kk.x); a16[2]  = fmaf(t.x, xd, a16[2]);  a16[3]  = fmaf(t.y, xd, a16[3]);
        t = d4_2(kk.x); a16[4]  = fmaf(t.x, xd, a16[4]);  a16[5]  = fmaf(t.y, xd, a16[5]);
        t = d4_3(kk.x); a16[6]  = fmaf(t.x, xd, a16[6]);  a16[7]  = fmaf(t.y, xd, a16[7]);
        t = d4_0(kk.y); a16[8]  = fmaf(t.x, xd, a16[8]);  a16[9]  = fmaf(t.y, xd, a16[9]);
        t = d4_1(kk.y); a16[10] = fmaf(t.x, xd, a16[10]); a16[11] = fmaf(t.y, xd, a16[11]);
        t = d4_2(kk.y); a16[12] = fmaf(t.x, xd, a16[12]); a16[13] = fmaf(t.y, xd, a16[13]);
        t = d4_3(kk.y); a16[14] = fmaf(t.x, xd, a16[14]); a16[15] = fmaf(t.y, xd, a16[15]);
    }
    // reduce across the 8 d-lanes (lane bits 3,4,5)
    #pragma unroll
    for (int j = 0; j < 16; ++j) {
        a16[j] += __shfl_xor(a16[j], 8);
        a16[j] += __shfl_xor(a16[j], 16);
        a16[j] += __shfl_xor(a16[j], 32);
    }
    if (lane < 8) {
        const int base = ((w << 3) + lane) * 16;
        #pragma unroll
        for (int j = 0; j < 16; j += 4)
            *(float4*)&sc[base + j] = make_float4(a16[j], a16[j+1], a16[j+2], a16[j+3]);
    }
    __syncthreads();

    // ---- softmax over 1024 scores (2 per thread) ----
    const float scl = 0.088388347648318447f;  // 1/sqrt(128)
    float s1v = sc[tid] * scl;
    float s2v = sc[tid + 512] * scl;
    float m = fmaxf(s1v, s2v);
    #pragma unroll
    for (int off = 1; off < 64; off <<= 1)
        m = fmaxf(m, __shfl_xor(m, off));
    if (lane == 0) wred[w] = m;
    __syncthreads();
    float M = wred[0];
    #pragma unroll
    for (int i = 1; i < 8; ++i) M = fmaxf(M, wred[i]);

    const float e1 = __expf(s1v - M);
    const float e2 = __expf(s2v - M);
    sc[tid] = e1;
    sc[tid + 512] = e2;
    float l = e1 + e2;
    #pragma unroll
    for (int off = 1; off < 64; off <<= 1)
        l += __shfl_xor(l, off);
    if (lane == 0) lred[w] = l;
    __syncthreads();   // probs + lred visible
    float Lsum = lred[0];
    #pragma unroll
    for (int i = 1; i < 8; ++i) Lsum += lred[i];

    // ---- PV: thread owns 16 dims, 16 rows; coalesced 512B/instr ----
    const int rg = tid >> 3;          // 0..63
    const int dg = tid & 7;           // 16 dims each
    const uchar* __restrict__ vg = vb + ((size_t)h * SLEN + (size_t)sp * CHUNK) * VROW;
    float acc[16];
    #pragma unroll
    for (int j = 0; j < 16; ++j) acc[j] = 0.f;
    #pragma unroll
    for (int it = 0; it < 16; ++it) {
        const int s1 = rg + it * 64;
        const u2v* vp = (const u2v*)(vg + (size_t)s1 * VROW + dg * 8);
        const u2v vv = (it >= 14) ? __builtin_nontemporal_load(vp) : *vp;
        const float pp = sc[s1];
        f2v t;
        t = d4_0(vv.x); acc[0]  = fmaf(pp, t.x, acc[0]);  acc[1]  = fmaf(pp, t.y, acc[1]);
        t = d4_1(vv.x); acc[2]  = fmaf(pp, t.x, acc[2]);  acc[3]  = fmaf(pp, t.y, acc[3]);
        t = d4_2(vv.x); acc[4]  = fmaf(pp, t.x, acc[4]);  acc[5]  = fmaf(pp, t.y, acc[5]);
        t = d4_3(vv.x); acc[6]  = fmaf(pp, t.x, acc[6]);  acc[7]  = fmaf(pp, t.y, acc[7]);
        t = d4_0(vv.y); acc[8]  = fmaf(pp, t.x, acc[8]);  acc[9]  = fmaf(pp, t.y, acc[9]);
        t = d4_1(vv.y); acc[10] = fmaf(pp, t.x, acc[10]); acc[11] = fmaf(pp, t.y, acc[11]);
        t = d4_2(vv.y); acc[12] = fmaf(pp, t.x, acc[12]); acc[13] = fmaf(pp, t.y, acc[13]);
        t = d4_3(vv.y); acc[14] = fmaf(pp, t.x, acc[14]); acc[15] = fmaf(pp, t.y, acc[15]);
    }
    // reduce across the wave's 8 row-groups (lane bits 3,4,5)
    #pragma unroll
    for (int j = 0; j < 16; ++j) {
        acc[j] += __shfl_xor(acc[j], 8);
        acc[j] += __shfl_xor(acc[j], 16);
        acc[j] += __shfl_xor(acc[j], 32);
    }
    if (lane < 8) {
        #pragma unroll
        for (int j = 0; j < 16; j += 4)
            *(float4*)&scpv[w][lane * 16 + j] = make_float4(acc[j], acc[j+1], acc[j+2], acc[j+3]);
    }
    __syncthreads();

    // ---- write partial (coalesced) ----
    float* __restrict__ ph = part_out + ((size_t)h * SPLITS + sp) * PART_STRIDE;
    if (tid < HEAD_DIM) {
        float a = 0.f;
        #pragma unroll
        for (int g = 0; g < 8; ++g) a += scpv[g][tid];
        ph[2 + tid] = a;
    }
    if (tid == 0) { ph[0] = M; ph[1] = Lsum; }
}

__global__ __launch_bounds__(128)
void attn_combine(const float* __restrict__ part, float* __restrict__ xout)
{
    xout[blockIdx.x * HEAD_DIM + threadIdx.x] =
        combine_head(part + (size_t)blockIdx.x * SPLITS * PART_STRIDE, threadIdx.x);
}

extern "C" void kernel_launch(void* const* d_in, const int* in_sizes, int n_in,
                              void* d_out, int out_size, void* d_ws, size_t ws_size,
                              hipStream_t stream)
{
    const float* x = (const float*)d_in[0];
    const float* k = (const float*)d_in[1];
    const float* v = (const float*)d_in[2];
    float* out = (float*)d_out;

    const size_t kvN = (size_t)NHEADS * SLEN * HEAD_DIM;       // 33,554,432
    const size_t partElems = (size_t)NHEADS * SPLITS * PART_STRIDE;

    float* part0 = (float*)d_ws;
    float* part1 = part0 + partElems;

    const size_t needWs = 2 * partElems * sizeof(float) + kvN;  // fp4 K^T + V
    uchar* kbt;
    uchar* vb;
    const bool ws_path = (ws_size >= needWs + 256);
    if (ws_path) kbt = (uchar*)(part1 + partElems);
    else         kbt = (uchar*)out;   // scratch in out K/V region; copy_kv at end
    vb = kbt + kvN / 2;

    if (ws_path) {
        convert_kT<true><<<NHEADS * 128, 256, 0, stream>>>(k, kbt, out);
        convert_v<true><<<2048, 256, 0, stream>>>(
            v, (u2v*)vb, out + kvN, kvN / 16);
    } else {
        convert_kT<false><<<NHEADS * 128, 256, 0, stream>>>(k, kbt, nullptr);
        convert_v<false><<<2048, 256, 0, stream>>>(
            v, (u2v*)vb, nullptr, kvN / 16);
    }

    for (int layer = 0; layer < NLAYERS; ++layer) {
        float* pout = (layer & 1) ? part1 : part0;
        const float* pin = (layer == 0) ? nullptr : ((layer & 1) ? part0 : part1);
        attn_layer<<<NHEADS * SPLITS, 512, 0, stream>>>(
            (layer == 0) ? x : nullptr, pin, kbt, vb, pout);
    }
    attn_combine<<<NHEADS, 128, 0, stream>>>(part1, out + 2 * kvN);  // layer 31 -> part1

    if (!ws_path) {
        copy_kv<<<2048, 256, 0, stream>>>((const float4*)k, (const float4*)v,
                                          (float4*)out, kvN / 4);
    }
}

// Round 12
// 415.288 us; speedup vs baseline: 1.3578x; 1.3578x over previous
//
#include <hip/hip_runtime.h>
#include <math.h>

#define HEAD_DIM 128
#define NHEADS   32
#define SPLITS   16
#define SLEN     8192
#define CHUNK    (SLEN / SPLITS)   /* 512 */
#define NLAYERS  32
#define PART_STRIDE (HEAD_DIM + 2) /* m, l, acc[128] */
#define KROW     (SLEN / 2)        /* K^T fp4 row bytes = 4096 */
#define VROW     (HEAD_DIM / 2)    /* V fp4 row bytes = 64 */
#define SCP_STR  20                /* padded stride per 16-score group */

typedef unsigned int   uint;
typedef unsigned char  uchar;
typedef __attribute__((ext_vector_type(2))) float f2v;

// ---- fp4 e2m1 hardware converters (gfx950), scale = 1.0 ----
__device__ __forceinline__ f2v d4_0(uint w) { return __builtin_amdgcn_cvt_scalef32_pk_f32_fp4(w, 1.0f, 0); }
__device__ __forceinline__ f2v d4_1(uint w) { return __builtin_amdgcn_cvt_scalef32_pk_f32_fp4(w, 1.0f, 1); }
__device__ __forceinline__ f2v d4_2(uint w) { return __builtin_amdgcn_cvt_scalef32_pk_f32_fp4(w, 1.0f, 2); }
__device__ __forceinline__ f2v d4_3(uint w) { return __builtin_amdgcn_cvt_scalef32_pk_f32_fp4(w, 1.0f, 3); }

__device__ __forceinline__ uint pk8_fp4(float a0, float a1, float a2, float a3,
                                        float a4, float a5, float a6, float a7) {
    uint r = 0;
    r = __builtin_amdgcn_cvt_scalef32_pk_fp4_f32(r, a0, a1, 1.0f, 0);
    r = __builtin_amdgcn_cvt_scalef32_pk_fp4_f32(r, a2, a3, 1.0f, 1);
    r = __builtin_amdgcn_cvt_scalef32_pk_fp4_f32(r, a4, a5, 1.0f, 2);
    r = __builtin_amdgcn_cvt_scalef32_pk_fp4_f32(r, a6, a7, 1.0f, 3);
    return r;
}

// ---- K: fp32 [h][s][d] -> fp4 TRANSPOSED [h][d][s] (+ optional fp32 copy-out) ----
template<bool WRITE_OUT>
__global__ __launch_bounds__(256)
void convert_kT(const float* __restrict__ k, uchar* __restrict__ kbt,
                float* __restrict__ kout)
{
    const int h   = blockIdx.x >> 7;      // 128 s-tiles of 64 per head
    const int st  = blockIdx.x & 127;
    const int tid = threadIdx.x;

    __shared__ float tile[HEAD_DIM][65];

    const int   srow0 = tid >> 5;
    const int   c4    = (tid & 31) * 4;
    const size_t kbase = ((size_t)h * SLEN + (size_t)st * 64) * HEAD_DIM;

    #pragma unroll
    for (int it = 0; it < 8; ++it) {
        const int s = srow0 + it * 8;
        const float4 v = *(const float4*)(k + kbase + (size_t)s * HEAD_DIM + c4);
        if (WRITE_OUT) *(float4*)(kout + kbase + (size_t)s * HEAD_DIM + c4) = v;
        tile[c4 + 0][s] = v.x; tile[c4 + 1][s] = v.y;
        tile[c4 + 2][s] = v.z; tile[c4 + 3][s] = v.w;
    }
    __syncthreads();

    const int d0  = tid >> 3;
    const int sl8 = (tid & 7) * 8;
    #pragma unroll
    for (int it = 0; it < 4; ++it) {
        const int d = d0 + it * 32;
        const uint u = pk8_fp4(tile[d][sl8 + 0], tile[d][sl8 + 1],
                               tile[d][sl8 + 2], tile[d][sl8 + 3],
                               tile[d][sl8 + 4], tile[d][sl8 + 5],
                               tile[d][sl8 + 6], tile[d][sl8 + 7]);
        *(uint*)(kbt + ((size_t)h * HEAD_DIM + d) * KROW + st * 32 + (tid & 7) * 4) = u;
    }
}

// ---- V: fp32 -> fp4 row-major (+ optional fp32 copy-out) ----
template<bool WRITE_OUT>
__global__ void convert_v(const float4* __restrict__ v, uint2* __restrict__ vb,
                          float4* __restrict__ vout, size_t n16)
{
    size_t i = (size_t)blockIdx.x * blockDim.x + threadIdx.x;
    const size_t stride = (size_t)gridDim.x * blockDim.x;
    for (size_t j = i; j < n16; j += stride) {
        const float4 b0 = v[4 * j], b1 = v[4 * j + 1], b2 = v[4 * j + 2], b3 = v[4 * j + 3];
        if (WRITE_OUT) {
            vout[4 * j] = b0; vout[4 * j + 1] = b1;
            vout[4 * j + 2] = b2; vout[4 * j + 3] = b3;
        }
        uint2 p;
        p.x = pk8_fp4(b0.x, b0.y, b0.z, b0.w, b1.x, b1.y, b1.z, b1.w);
        p.y = pk8_fp4(b2.x, b2.y, b2.z, b2.w, b3.x, b3.y, b3.z, b3.w);
        vb[j] = p;
    }
}

// ---- fallback copy ----
__global__ void copy_kv(const float4* __restrict__ k, const float4* __restrict__ v,
                        float4* __restrict__ out, size_t n4)
{
    size_t i = (size_t)blockIdx.x * blockDim.x + threadIdx.x;
    const size_t stride = (size_t)gridDim.x * blockDim.x;
    for (size_t j = i; j < n4; j += stride) {
        out[j]      = k[j];
        out[n4 + j] = v[j];
    }
}

__device__ __forceinline__ float combine_head(const float* __restrict__ ph, int d)
{
    float G = -3.0e38f;
    #pragma unroll
    for (int i = 0; i < SPLITS; ++i) G = fmaxf(G, ph[i * PART_STRIDE]);
    float L = 0.f, a = 0.f;
    #pragma unroll
    for (int i = 0; i < SPLITS; ++i) {
        const float wv = __expf(ph[i * PART_STRIDE] - G);
        L = fmaf(ph[i * PART_STRIDE + 1], wv, L);
        a = fmaf(ph[i * PART_STRIDE + 2 + d], wv, a);
    }
    return a / L;
}

// ---- one layer: 512 blocks (2/CU) x 512 threads; chunk = 512 rows ----
__global__ __launch_bounds__(512)
void attn_layer(const float* __restrict__ x0,
                const float* __restrict__ part_in,
                const uchar* __restrict__ kbt,   // fp4 K^T [32][128][8192]
                const uchar* __restrict__ vb,    // fp4 V   [32][8192][128]
                float* __restrict__ part_out)
{
    const int h    = blockIdx.x >> 4;
    const int sp   = blockIdx.x & 15;
    const int tid  = threadIdx.x;   // 0..511
    const int lane = tid & 63;
    const int w    = tid >> 6;      // 0..7

    __shared__ float xs[HEAD_DIM];
    __shared__ float scp[8][32 * SCP_STR];  // 20 KB: per-wave QK partials (padded)
    __shared__ float sc[CHUNK];             // 2 KB: probs
    __shared__ float scpv[8][HEAD_DIM];     // 4 KB: per-wave PV partials
    __shared__ float wred[8], lred[8];

    // ---- prologue: produce x for this head (16-split combine) ----
    if (tid < HEAD_DIM) {
        if (part_in) xs[tid] = combine_head(part_in + (size_t)h * SPLITS * PART_STRIDE, tid);
        else         xs[tid] = x0[h * HEAD_DIM + tid];
    }
    __syncthreads();

    // ---- QK: lane owns 16 consecutive s for 8 d values ----
    // one wave instr: 2 d-rows x 256B contiguous = 512B coalesced
    const int dpar = lane >> 5;              // 0..1
    const int sgp  = lane & 31;              // 16-s group 0..31
    const uchar* __restrict__ kh = kbt + (size_t)h * HEAD_DIM * KROW + (size_t)sp * (CHUNK / 2);
    float a16[16];
    #pragma unroll
    for (int j = 0; j < 16; ++j) a16[j] = 0.f;
    #pragma unroll
    for (int it = 0; it < 8; ++it) {
        const int d = it * 16 + (w << 1) + dpar;
        const uint2 kk = *(const uint2*)(kh + (size_t)d * KROW + sgp * 8);
        const float xd = xs[d];
        f2v t;
        t = d4_0(kk.x); a16[0]  = fmaf(t.x, xd, a16[0]);  a16[1]  = fmaf(t.y, xd, a16[1]);
        t = d4_1(kk.x); a16[2]  = fmaf(t.x, xd, a16[2]);  a16[3]  = fmaf(t.y, xd, a16[3]);
        t = d4_2(kk.x); a16[4]  = fmaf(t.x, xd, a16[4]);  a16[5]  = fmaf(t.y, xd, a16[5]);
        t = d4_3(kk.x); a16[6]  = fmaf(t.x, xd, a16[6]);  a16[7]  = fmaf(t.y, xd, a16[7]);
        t = d4_0(kk.y); a16[8]  = fmaf(t.x, xd, a16[8]);  a16[9]  = fmaf(t.y, xd, a16[9]);
        t = d4_1(kk.y); a16[10] = fmaf(t.x, xd, a16[10]); a16[11] = fmaf(t.y, xd, a16[11]);
        t = d4_2(kk.y); a16[12] = fmaf(t.x, xd, a16[12]); a16[13] = fmaf(t.y, xd, a16[13]);
        t = d4_3(kk.y); a16[14] = fmaf(t.x, xd, a16[14]); a16[15] = fmaf(t.y, xd, a16[15]);
    }
    // sum the two d-parities (lane ^ 32)
    #pragma unroll
    for (int j = 0; j < 16; ++j) a16[j] += __shfl_xor(a16[j], 32);
    if (lane < 32) {
        #pragma unroll
        for (int j = 0; j < 16; j += 4)
            *(float4*)&scp[w][sgp * SCP_STR + j] =
                make_float4(a16[j], a16[j+1], a16[j+2], a16[j+3]);
    }
    __syncthreads();

    // ---- gather score (sum 8 wave-partials), softmax over 512 (1/thread) ----
    const int soff = (tid >> 4) * SCP_STR + (tid & 15);
    float s = scp[0][soff] + scp[1][soff] + scp[2][soff] + scp[3][soff]
            + scp[4][soff] + scp[5][soff] + scp[6][soff] + scp[7][soff];
    s *= 0.088388347648318447f;  // 1/sqrt(128)

    float m = s;
    #pragma unroll
    for (int off = 1; off < 64; off <<= 1)
        m = fmaxf(m, __shfl_xor(m, off));
    if (lane == 0) wred[w] = m;
    __syncthreads();
    float M = wred[0];
    #pragma unroll
    for (int i = 1; i < 8; ++i) M = fmaxf(M, wred[i]);

    const float e = __expf(s - M);
    sc[tid] = e;
    float l = e;
    #pragma unroll
    for (int off = 1; off < 64; off <<= 1)
        l += __shfl_xor(l, off);
    if (lane == 0) lred[w] = l;
    __syncthreads();   // probs + lred visible
    float Lsum = lred[0];
    #pragma unroll
    for (int i = 1; i < 8; ++i) Lsum += lred[i];

    // ---- PV: thread owns 16 dims, 8 rows; coalesced 512B/instr ----
    const int rg = tid >> 3;          // 0..63
    const int dg = tid & 7;           // 16 dims each
    const uchar* __restrict__ vg = vb + ((size_t)h * SLEN + (size_t)sp * CHUNK) * VROW;
    float acc[16];
    #pragma unroll
    for (int j = 0; j < 16; ++j) acc[j] = 0.f;
    #pragma unroll
    for (int it = 0; it < 8; ++it) {
        const int s1 = rg + it * 64;
        const uint2 vv = *(const uint2*)(vg + (size_t)s1 * VROW + dg * 8);
        const float pp = sc[s1];
        f2v t;
        t = d4_0(vv.x); acc[0]  = fmaf(pp, t.x, acc[0]);  acc[1]  = fmaf(pp, t.y, acc[1]);
        t = d4_1(vv.x); acc[2]  = fmaf(pp, t.x, acc[2]);  acc[3]  = fmaf(pp, t.y, acc[3]);
        t = d4_2(vv.x); acc[4]  = fmaf(pp, t.x, acc[4]);  acc[5]  = fmaf(pp, t.y, acc[5]);
        t = d4_3(vv.x); acc[6]  = fmaf(pp, t.x, acc[6]);  acc[7]  = fmaf(pp, t.y, acc[7]);
        t = d4_0(vv.y); acc[8]  = fmaf(pp, t.x, acc[8]);  acc[9]  = fmaf(pp, t.y, acc[9]);
        t = d4_1(vv.y); acc[10] = fmaf(pp, t.x, acc[10]); acc[11] = fmaf(pp, t.y, acc[11]);
        t = d4_2(vv.y); acc[12] = fmaf(pp, t.x, acc[12]); acc[13] = fmaf(pp, t.y, acc[13]);
        t = d4_3(vv.y); acc[14] = fmaf(pp, t.x, acc[14]); acc[15] = fmaf(pp, t.y, acc[15]);
    }
    // reduce across the wave's 8 row-groups (lane bits 3,4,5)
    #pragma unroll
    for (int j = 0; j < 16; ++j) {
        acc[j] += __shfl_xor(acc[j], 8);
        acc[j] += __shfl_xor(acc[j], 16);
        acc[j] += __shfl_xor(acc[j], 32);
    }
    if (lane < 8) {
        #pragma unroll
        for (int j = 0; j < 16; j += 4)
            *(float4*)&scpv[w][lane * 16 + j] = make_float4(acc[j], acc[j+1], acc[j+2], acc[j+3]);
    }
    __syncthreads();

    // ---- write partial (coalesced) ----
    float* __restrict__ ph = part_out + ((size_t)h * SPLITS + sp) * PART_STRIDE;
    if (tid < HEAD_DIM) {
        float a = 0.f;
        #pragma unroll
        for (int g = 0; g < 8; ++g) a += scpv[g][tid];
        ph[2 + tid] = a;
    }
    if (tid == 0) { ph[0] = M; ph[1] = Lsum; }
}

__global__ __launch_bounds__(128)
void attn_combine(const float* __restrict__ part, float* __restrict__ xout)
{
    xout[blockIdx.x * HEAD_DIM + threadIdx.x] =
        combine_head(part + (size_t)blockIdx.x * SPLITS * PART_STRIDE, threadIdx.x);
}

extern "C" void kernel_launch(void* const* d_in, const int* in_sizes, int n_in,
                              void* d_out, int out_size, void* d_ws, size_t ws_size,
                              hipStream_t stream)
{
    const float* x = (const float*)d_in[0];
    const float* k = (const float*)d_in[1];
    const float* v = (const float*)d_in[2];
    float* out = (float*)d_out;

    const size_t kvN = (size_t)NHEADS * SLEN * HEAD_DIM;       // 33,554,432
    const size_t partElems = (size_t)NHEADS * SPLITS * PART_STRIDE;

    float* part0 = (float*)d_ws;
    float* part1 = part0 + partElems;

    const size_t needWs = 2 * partElems * sizeof(float) + kvN;  // fp4 K^T + V
    uchar* kbt;
    uchar* vb;
    const bool ws_path = (ws_size >= needWs + 256);
    if (ws_path) kbt = (uchar*)(part1 + partElems);
    else         kbt = (uchar*)out;   // scratch in out K/V region; copy_kv at end
    vb = kbt + kvN / 2;

    if (ws_path) {
        convert_kT<true><<<NHEADS * 128, 256, 0, stream>>>(k, kbt, out);
        convert_v<true><<<2048, 256, 0, stream>>>(
            (const float4*)v, (uint2*)vb, (float4*)(out + kvN), kvN / 16);
    } else {
        convert_kT<false><<<NHEADS * 128, 256, 0, stream>>>(k, kbt, nullptr);
        convert_v<false><<<2048, 256, 0, stream>>>(
            (const float4*)v, (uint2*)vb, nullptr, kvN / 16);
    }

    for (int layer = 0; layer < NLAYERS; ++layer) {
        float* pout = (layer & 1) ? part1 : part0;
        const float* pin = (layer == 0) ? nullptr : ((layer & 1) ? part0 : part1);
        attn_layer<<<NHEADS * SPLITS, 512, 0, stream>>>(
            (layer == 0) ? x : nullptr, pin, kbt, vb, pout);
    }
    attn_combine<<<NHEADS, 128, 0, stream>>>(part1, out + 2 * kvN);  // layer 31 -> part1

    if (!ws_path) {
        copy_kv<<<2048, 256, 0, stream>>>((const float4*)k, (const float4*)v,
                                          (float4*)out, kvN / 4);
    }
}